// Round 12
// baseline (81.076 us; speedup 1.0000x reference)
//
#include <hip/hip_runtime.h>

// Fused, reads p once, writes out once. Per (b, 4-row strip):
//  phase 1 (r10-verified shape): 16 chunks of 8 channels through XOR-swizzled
//    slab, 2-deep reg prefetch, 2 barriers/chunk; accumulate 9 sums
//    S_d = sum_c p[x]*p[x+d]; retain center quads in 16 NAMED float4 regs.
//  phase 2: inv = 1/sqrt(S_center) (+halo), sim = (1/9)*inv*sum_d inv[x+d]*S_d,
//    computed in BOTH chalf lanes.
//  phase 3 (r11-verified): lane-pair exchange via __shfl_xor(,1) (DPP), direct
//    global stores; no LDS, no barriers, no conflicts.
// __launch_bounds__(256, 1): min-waves/EU=1 relaxes the VGPR cap — rounds 10/11
// proved the default allocator pins 64 VGPR and spills keep (WRITE 160-175 MB
// vs 134 ideal). Decisive counters: VGPR>=110 and WRITE~134 MB.

__device__ __forceinline__ float dot4acc(float4 a, float4 b, float acc) {
    acc = fmaf(a.x, b.x, acc);
    acc = fmaf(a.y, b.y, acc);
    acc = fmaf(a.z, b.z, acc);
    acc = fmaf(a.w, b.w, acc);
    return acc;
}

__global__ __launch_bounds__(256, 1)
void bcim_fused(const float* __restrict__ p, float* __restrict__ out) {
    __shared__ float slab[1536];   // [6 rows][64 quads][4]
    __shared__ float invL[192];

    const int tid = threadIdx.x;
    const int b  = blockIdx.x >> 3;
    const int r0 = (blockIdx.x & 7) << 2;
    const float* __restrict__ pb = p + (size_t)b * 131072;

    // ---- loader mapping (v3-verified) ----
    const int l_wq = tid & 7;
    const int l_c  = (tid >> 3) & 7;
    const int l_r  = tid >> 6;
    const int g0r  = r0 - 1 + l_r;
    const int g1r  = r0 + 3 + l_r;
    const bool in0 = ((unsigned)g0r < 32u);
    const bool in1 = (tid < 128) && ((unsigned)g1r < 32u);
    int wOff[4];
    {
        const int chh = l_c >> 2;
        const int ci  = l_c & 3;
        #pragma unroll
        for (int j = 0; j < 4; ++j) {
            const int u = ((l_wq << 3) + (j << 1) + chh) ^ l_wq;
            wOff[j] = l_r * 256 + u * 4 + ci;
        }
    }
    const int gOff0 = l_c * 1024 + g0r * 32 + l_wq * 4;
    const int gOff1 = l_c * 1024 + g1r * 32 + l_wq * 4;

    // ---- stencil mapping (v3-verified) ----
    const int chalf = tid & 1;
    const int pos   = tid >> 1;
    const int h     = pos >> 5;
    const int w     = pos & 31;
    const int wm    = (w > 0) ? w - 1 : 0;
    const int wp    = (w < 31) ? w + 1 : 31;
    const int uc    = (w  * 2 + chalf) ^ (w  >> 2);
    const int um    = (wm * 2 + chalf) ^ (wm >> 2);
    const int up    = (wp * 2 + chalf) ^ (wp >> 2);

    const float4 z4 = make_float4(0.f, 0.f, 0.f, 0.f);
    float4 A0 = z4, A1 = z4, B0 = z4, B1 = z4;
    if (in0) A0 = *(const float4*)(pb + gOff0);
    if (in1) A1 = *(const float4*)(pb + gOff1);
    if (in0) B0 = *(const float4*)(pb + 8192 + gOff0);
    if (in1) B1 = *(const float4*)(pb + 8192 + gOff1);

    float s0=0.f,s1=0.f,s2=0.f,s3=0.f,s4=0.f,s5=0.f,s6=0.f,s7=0.f,s8=0.f,hn=0.f;
    float4 K00, K01, K02, K03, K04, K05, K06, K07;
    float4 K08, K09, K10, K11, K12, K13, K14, K15;

    #define STEP(R0, R1, NEXTC, KVAR) {                                             \
        slab[wOff[0]] = R0.x; slab[wOff[1]] = R0.y;                                 \
        slab[wOff[2]] = R0.z; slab[wOff[3]] = R0.w;                                 \
        if (tid < 128) {                                                            \
            slab[wOff[0] + 1024] = R1.x; slab[wOff[1] + 1024] = R1.y;               \
            slab[wOff[2] + 1024] = R1.z; slab[wOff[3] + 1024] = R1.w;               \
        }                                                                           \
        __syncthreads();                                                            \
        if ((NEXTC) < 16) {                                                         \
            if (in0) R0 = *(const float4*)(pb + (NEXTC) * 8192 + gOff0);            \
            if (in1) R1 = *(const float4*)(pb + (NEXTC) * 8192 + gOff1);            \
        }                                                                           \
        {                                                                           \
            const float4* sp = (const float4*)slab;                                 \
            const float4 ctr = sp[(h + 1) * 64 + uc];                               \
            KVAR = ctr;                                                             \
            float4 n0 = sp[h * 64 + um];                                            \
            float4 n1 = sp[h * 64 + uc];                                            \
            float4 n2 = sp[h * 64 + up];                                            \
            s0 = dot4acc(ctr, n0, s0);                                              \
            s1 = dot4acc(ctr, n1, s1);                                              \
            s2 = dot4acc(ctr, n2, s2);                                              \
            if (h == 0) hn = dot4acc(n1, n1, hn);                                   \
            n0 = sp[(h + 2) * 64 + um];                                             \
            n1 = sp[(h + 2) * 64 + uc];                                             \
            n2 = sp[(h + 2) * 64 + up];                                             \
            s6 = dot4acc(ctr, n0, s6);                                              \
            s7 = dot4acc(ctr, n1, s7);                                              \
            s8 = dot4acc(ctr, n2, s8);                                              \
            if (h == 3) hn = dot4acc(n1, n1, hn);                                   \
            n0 = sp[(h + 1) * 64 + um];                                             \
            n2 = sp[(h + 1) * 64 + up];                                             \
            s3 = dot4acc(ctr, n0, s3);                                              \
            s4 = dot4acc(ctr, ctr, s4);                                             \
            s5 = dot4acc(ctr, n2, s5);                                              \
        }                                                                           \
        __syncthreads(); }

    STEP(A0, A1,  2, K00)  STEP(B0, B1,  3, K01)
    STEP(A0, A1,  4, K02)  STEP(B0, B1,  5, K03)
    STEP(A0, A1,  6, K04)  STEP(B0, B1,  7, K05)
    STEP(A0, A1,  8, K06)  STEP(B0, B1,  9, K07)
    STEP(A0, A1, 10, K08)  STEP(B0, B1, 11, K09)
    STEP(A0, A1, 12, K10)  STEP(B0, B1, 13, K11)
    STEP(A0, A1, 14, K12)  STEP(B0, B1, 15, K13)
    STEP(A0, A1, 16, K14)  STEP(B0, B1, 17, K15)
    #undef STEP

    // pair-reduce channel halves (lanes 2k <-> 2k+1): both lanes get full sums
    s0 += __shfl_xor(s0, 1); s1 += __shfl_xor(s1, 1); s2 += __shfl_xor(s2, 1);
    s3 += __shfl_xor(s3, 1); s4 += __shfl_xor(s4, 1); s5 += __shfl_xor(s5, 1);
    s6 += __shfl_xor(s6, 1); s7 += __shfl_xor(s7, 1); s8 += __shfl_xor(s8, 1);
    hn += __shfl_xor(hn, 1);

    if (chalf == 0) {
        invL[(h + 1) * 32 + w] = (s4 > 0.f) ? (1.0f / sqrtf(s4)) : 0.f;
        if (h == 0) invL[w]       = (hn > 0.f) ? (1.0f / sqrtf(hn)) : 0.f;
        if (h == 3) invL[160 + w] = (hn > 0.f) ? (1.0f / sqrtf(hn)) : 0.f;
    }
    __syncthreads();

    float simreg;
    {
        const float mL = (w > 0)  ? 1.f : 0.f;
        const float mR = (w < 31) ? 1.f : 0.f;
        const float* iT = invL + h * 32;
        const float* iM = iT + 32;
        const float* iB = iM + 32;
        float acc;
        acc = s0 * (iT[wm] * mL);
        acc = fmaf(s1, iT[w],       acc);
        acc = fmaf(s2, iT[wp] * mR, acc);
        acc = fmaf(s3, iM[wm] * mL, acc);
        acc = fmaf(s4, iM[w],       acc);
        acc = fmaf(s5, iM[wp] * mR, acc);
        acc = fmaf(s6, iB[wm] * mL, acc);
        acc = fmaf(s7, iB[w],       acc);
        acc = fmaf(s8, iB[wp] * mR, acc);
        simreg = acc * iM[w] * (1.0f / 9.0f);
    }

    // ---- phase 3 (r11-verified): lane-pair DPP exchange, direct stores ----
    // lane (pos, chalf) holds KVAR(ch) = p[ch*8 + chalf*4 + (0..3), pos].
    float* op = out + (size_t)b * 131072 + (size_t)chalf * 65536 +
                (size_t)(r0 + h) * 2048 + (size_t)w * 64;
    #define OUTQ(KVAR, CH) {                                                        \
        float4 kk = KVAR;                                                           \
        kk.x *= simreg; kk.y *= simreg; kk.z *= simreg; kk.w *= simreg;             \
        const float sA = chalf ? kk.x : kk.y;                                       \
        const float sB = chalf ? kk.z : kk.w;                                       \
        const float eA = __shfl_xor(sA, 1);                                         \
        const float eB = __shfl_xor(sB, 1);                                         \
        float4 o;                                                                   \
        if (chalf == 0) { o.x = kk.x; o.y = kk.z; o.z = eA;   o.w = eB;   }         \
        else            { o.x = eA;   o.y = eB;   o.z = kk.y; o.w = kk.w; }         \
        *(float4*)(op + (CH) * 4) = o; }

    OUTQ(K00,  0) OUTQ(K01,  1) OUTQ(K02,  2) OUTQ(K03,  3)
    OUTQ(K04,  4) OUTQ(K05,  5) OUTQ(K06,  6) OUTQ(K07,  7)
    OUTQ(K08,  8) OUTQ(K09,  9) OUTQ(K10, 10) OUTQ(K11, 11)
    OUTQ(K12, 12) OUTQ(K13, 13) OUTQ(K14, 14) OUTQ(K15, 15)
    #undef OUTQ
}

extern "C" void kernel_launch(void* const* d_in, const int* in_sizes, int n_in,
                              void* d_out, int out_size, void* d_ws, size_t ws_size,
                              hipStream_t stream) {
    const float* p = (const float*)d_in[0];
    float* out = (float*)d_out;
    bcim_fused<<<dim3(2048), dim3(256), 0, stream>>>(p, out);
    (void)in_sizes; (void)n_in; (void)out_size; (void)d_ws; (void)ws_size;
}